// Round 6
// baseline (325.479 us; speedup 1.0000x reference)
//
#include <hip/hip_runtime.h>
#include <hip/hip_bf16.h>

// sim[b,l,m] = sum_d relu(prev@W+b)[b,l,d] * relu(after@W+b)[b,m,d]
// bz=16, L=2048, d=768.
//
// Pipeline:
//   1. wt_kernel : Wt[n][k] = bf16(W[k][n])                       (ws, 1.2 MB)
//   2. conv x2   : Sb = bf16(seq_prev ++ seq_after) [65536][768]  (d_out scratch)
//   3. gemm1     : Pboth = relu(Sb @ Wt^T + bias) -> bf16         (ws, 96 MB)
//   4. gemm2     : sim[b] = Pp[b] @ Pa[b]^T -> fp32 d_out
//
// GEMM: m201-style fine-phase schedule: 256x256 tile, BK=64, 8 waves (2Mx4N),
// double-buffered 128KB LDS, global_load_lds w/ pre-swizzled source
// (XOR (row&7)<<4), 4 phases per K-tile each {ds_reads | stage | barrier |
// lgkmcnt(0) | setprio(1) 16 MFMA setprio(0) | barrier}, counted vmcnt(4)
// once per K-tile.
//
// ROUND 3/4 ROOT CAUSE: STAGE_J's local `int c` shadowed the caller's
// `const int c = kt & 1` while the macro arg `buf` was the TEXT `c ^ 1`,
// so lA[buf] indexed with the local c (garbage base). All macro locals are
// now underscore-prefixed. Barriers stay sched_barrier(0)-pinned.

typedef __attribute__((ext_vector_type(8))) short  bf16x8v;
typedef __attribute__((ext_vector_type(8))) short  s16x8;
typedef __attribute__((ext_vector_type(4))) float  f32x4;
typedef __attribute__((ext_vector_type(4))) float  float4v;

__device__ __forceinline__ unsigned short f2bf(float f) {
  unsigned int u = __float_as_uint(f);
  u += 0x7fffu + ((u >> 16) & 1u);
  return (unsigned short)(u >> 16);
}

__device__ __forceinline__ void async_copy16(void* lds, const void* g) {
  __builtin_amdgcn_global_load_lds(
      (const __attribute__((address_space(1))) void*)g,
      (__attribute__((address_space(3))) void*)lds, 16, 0, 0);
}

// pinned barrier: no instruction may cross it in either direction
#define BARF() do { __builtin_amdgcn_sched_barrier(0);                  \
                    __builtin_amdgcn_s_barrier();                       \
                    __builtin_amdgcn_sched_barrier(0); } while (0)
#define WAITV4() do { asm volatile("s_waitcnt vmcnt(4)" ::: "memory");  \
                      __builtin_amdgcn_sched_barrier(0); } while (0)
#define WAITV0() do { asm volatile("s_waitcnt vmcnt(0)" ::: "memory");  \
                      __builtin_amdgcn_sched_barrier(0); } while (0)
#define LGKM0()  do { asm volatile("s_waitcnt lgkmcnt(0)" ::: "memory");\
                      __builtin_amdgcn_sched_barrier(0); } while (0)

// ---------------- W transpose + convert: Wt[n][k] = bf16(W[k][n]) ------------
__global__ void wt_kernel(const float* __restrict__ W, short* __restrict__ Wt) {
  int idx = blockIdx.x * 256 + threadIdx.x;   // n*768 + k
  int n = idx / 768;
  int k = idx - n * 768;
  Wt[idx] = (short)f2bf(W[k * 768 + n]);
}

// ---------------- fp32 -> bf16 conversion (vectorized 8/thread) --------------
__global__ void conv_kernel(const float* __restrict__ X, short* __restrict__ Y, int n8) {
  int stride = gridDim.x * blockDim.x;
  for (int i = blockIdx.x * blockDim.x + threadIdx.x; i < n8; i += stride) {
    const float4v* Xv = (const float4v*)X;
    float4v a = Xv[2 * i];
    float4v b = Xv[2 * i + 1];
    s16x8 o;
    o[0] = (short)f2bf(a[0]); o[1] = (short)f2bf(a[1]);
    o[2] = (short)f2bf(a[2]); o[3] = (short)f2bf(a[3]);
    o[4] = (short)f2bf(b[0]); o[5] = (short)f2bf(b[1]);
    o[6] = (short)f2bf(b[2]); o[7] = (short)f2bf(b[3]);
    ((s16x8*)Y)[i] = o;
  }
}

// ---------------- phase-pipelined 256x256 GEMM (C = A @ B^T), K=768 ----------
// EPI 0: fp32 store   EPI 1: bias+relu -> bf16 store
template<int EPI>
__global__ __launch_bounds__(512, 2)
void gemm_pipe(const short* __restrict__ A, const short* __restrict__ B,
               const float* __restrict__ bias, void* __restrict__ Cout,
               int ldc, long long sA, long long sB, long long sC) {
  constexpr int BK = 64, KT = 12;             // K = 768
  __shared__ __align__(16) short lA[2][256 * BK];
  __shared__ __align__(16) short lB[2][256 * BK];

  const int tid  = threadIdx.x;
  const int lane = tid & 63;
  const int w    = tid >> 6;                  // 0..7
  const int wr   = w >> 2;                    // 0..1  (M half)
  const int wc   = w & 3;                     // 0..3  (N quarter)
  const int bz   = blockIdx.z;
  const int tm   = blockIdx.y * 256;
  const int tn   = blockIdx.x * 256;

  const short* Ab = A + (size_t)bz * sA + (size_t)tm * 768;
  const short* Bb = B + (size_t)bz * sB + (size_t)tn * 768;

  const int lrow = lane & 15;                 // fragment row within 16
  const int koff = (lane >> 4) * 16;          // byte offset of lane's k-slice
  const int sx   = (lrow & 7) << 4;           // XOR swizzle term

  // stage chunk j (rows j*64..j*64+63) of a K-tile: 2 global_load_lds.
  // ALL locals underscore-prefixed (macro hygiene — round-3/4 root cause).
#define STAGE_J(buf, k0, j)                                                   \
  {                                                                           \
    int _c    = (j) * 512 + tid;                                              \
    int _row  = _c >> 3;                                                      \
    int _colb = ((_c & 7) * 16) ^ ((_row & 7) << 4);                          \
    async_copy16((char*)lA[buf] + (j) * 8192 + w * 1024,                      \
                 (const char*)(Ab + (size_t)_row * 768 + (k0)) + _colb);      \
    async_copy16((char*)lB[buf] + (j) * 8192 + w * 1024,                      \
                 (const char*)(Bb + (size_t)_row * 768 + (k0)) + _colb);      \
  }

#define READ_A(dst, buf, mh, kk)                                              \
  {                                                                           \
    const char* _p = (const char*)lA[buf];                                    \
    const int  _kx = ((kk) * 64 + koff) ^ sx;                                 \
    _Pragma("unroll")                                                         \
    for (int _m = 0; _m < 4; ++_m)                                            \
      dst[_m] = *(const bf16x8v*)(_p + (wr * 128 + (mh) * 64 + _m * 16 + lrow) * 128 + _kx); \
  }

#define READ_B(dst, buf, kk)                                                  \
  {                                                                           \
    const char* _p = (const char*)lB[buf];                                    \
    const int  _kx = ((kk) * 64 + koff) ^ sx;                                 \
    _Pragma("unroll")                                                         \
    for (int _n = 0; _n < 4; ++_n)                                            \
      dst[_n] = *(const bf16x8v*)(_p + (wc * 64 + _n * 16 + lrow) * 128 + _kx); \
  }

#define MFMA_Q(mh, Af, Bf)                                                    \
  {                                                                           \
    __builtin_amdgcn_s_setprio(1);                                            \
    _Pragma("unroll")                                                         \
    for (int _m = 0; _m < 4; ++_m)                                            \
      _Pragma("unroll")                                                       \
      for (int _n = 0; _n < 4; ++_n)                                          \
        acc[(mh) * 4 + _m][_n] = __builtin_amdgcn_mfma_f32_16x16x32_bf16(     \
            Af[_m], Bf[_n], acc[(mh) * 4 + _m][_n], 0, 0, 0);                 \
    __builtin_amdgcn_s_setprio(0);                                            \
  }

  f32x4 acc[8][4] = {};
  bf16x8v a0[4], a1[4], a2[4], a3[4], b0[4], b1[4];

  // prologue: tile0 fully (8 loads) + tile1 chunks 0,1 (4 loads)
  STAGE_J(0, 0, 0); STAGE_J(0, 0, 1); STAGE_J(0, 0, 2); STAGE_J(0, 0, 3);
  STAGE_J(1, BK, 0); STAGE_J(1, BK, 1);
  WAITV4();                                   // tile0 landed (own loads)
  BARF();                                     // landed for everyone

  for (int kt = 0; kt < KT; ++kt) {
    const int cb = kt & 1;
    // ---- P0: quadrant (mh0,kk0) ----
    READ_A(a0, cb, 0, 0);
    READ_B(b0, cb, 0);
    if (kt + 1 < KT) STAGE_J(cb ^ 1, (kt + 1) * BK, 2);
    BARF(); LGKM0();
    MFMA_Q(0, a0, b0);
    BARF();
    // ---- P1: quadrant (mh1,kk0) ----
    READ_A(a1, cb, 1, 0);
    READ_A(a2, cb, 0, 1);
    READ_B(b1, cb, 1);
    if (kt + 1 < KT) STAGE_J(cb ^ 1, (kt + 1) * BK, 3);
    BARF(); LGKM0();
    MFMA_Q(1, a1, b0);
    BARF();
    // ---- P2: quadrant (mh0,kk1) ----
    READ_A(a3, cb, 1, 1);
    BARF(); LGKM0();
    MFMA_Q(0, a2, b1);
    BARF();                    // after this, nobody reads buf cb anymore
    // ---- P3: quadrant (mh1,kk1) + prefetch kt+2 into freed buf cb ----
    if (kt + 2 < KT) { STAGE_J(cb, (kt + 2) * BK, 0); STAGE_J(cb, (kt + 2) * BK, 1); }
    MFMA_Q(1, a3, b1);
    if (kt + 2 < KT)       { WAITV4(); }      // tile kt+1 fully landed (own)
    else if (kt + 2 == KT) { WAITV0(); }      // tail: drain for last tile
    if (kt + 1 < KT) BARF();                  // landed for everyone
  }

  // epilogue
#pragma unroll
  for (int m = 0; m < 8; ++m) {
    int row0 = tm + wr * 128 + m * 16 + (lane >> 4) * 4;
#pragma unroll
    for (int n = 0; n < 4; ++n) {
      int col = tn + wc * 64 + n * 16 + lrow;
      if (EPI == 0) {
        float* C = (float*)Cout + (size_t)bz * sC;
#pragma unroll
        for (int i = 0; i < 4; ++i)
          C[(size_t)(row0 + i) * ldc + col] = acc[m][n][i];
      } else {
        short* C = (short*)Cout + (size_t)bz * sC;
        float bv = bias[col];
#pragma unroll
        for (int i = 0; i < 4; ++i) {
          float v = fmaxf(acc[m][n][i] + bv, 0.0f);
          C[(size_t)(row0 + i) * ldc + col] = (short)f2bf(v);
        }
      }
    }
  }
#undef STAGE_J
#undef READ_A
#undef READ_B
#undef MFMA_Q
}

extern "C" void kernel_launch(void* const* d_in, const int* in_sizes, int n_in,
                              void* d_out, int out_size, void* d_ws, size_t ws_size,
                              hipStream_t stream) {
  const float* seq_prev  = (const float*)d_in[0];  // [16][2048][768]
  const float* seq_after = (const float*)d_in[1];  // [16][2048][768]
  const float* W         = (const float*)d_in[2];  // [768][768] (in,out)
  const float* bias      = (const float*)d_in[3];  // [768]
  float* out             = (float*)d_out;          // [16][2048][2048] fp32

  char* ws   = (char*)d_ws;
  short* Wt  = (short*)ws;                         // 768*768*2   = 1179648 B
  short* Pb  = (short*)(ws + 1179648);             // 65536*768*2 = 100663296 B
  short* Sb  = (short*)d_out;                      // scratch in d_out (96 MB)

  constexpr int NSEQ = 16 * 2048 * 768;
  constexpr int N8   = NSEQ / 8;

  // 1. W transpose + convert
  wt_kernel<<<768 * 768 / 256, 256, 0, stream>>>(W, Wt);

  // 2. convert both sequences to bf16 (into d_out scratch)
  conv_kernel<<<2048, 256, 0, stream>>>(seq_prev,  Sb,        N8);
  conv_kernel<<<2048, 256, 0, stream>>>(seq_after, Sb + NSEQ, N8);

  // 3. feed-forward + relu, both seqs at once: M=65536, N=768
  dim3 g1(3, 256, 1);
  gemm_pipe<1><<<g1, 512, 0, stream>>>(Sb, Wt, bias, Pb, 768, 0, 0, 0);

  // 4. batched similarity: sim[b] = Pp[b] @ Pa[b]^T  (M=N=2048 per batch)
  dim3 g2(8, 8, 16);
  gemm_pipe<0><<<g2, 512, 0, stream>>>(Pb, Pb + NSEQ, nullptr, out,
                                       2048, 2048 * 768, 2048 * 768,
                                       2048LL * 2048);
}

// Round 7
// 312.753 us; speedup vs baseline: 1.0407x; 1.0407x over previous
//
#include <hip/hip_runtime.h>
#include <hip/hip_bf16.h>

// sim[b,l,m] = sum_d relu(prev@W+b)[b,l,d] * relu(after@W+b)[b,m,d]
// bz=16, L=2048, d=768.
//
// Pipeline:
//   1. wt_kernel : Wt[n][k] = bf16(W[k][n])                       (ws, 1.2 MB)
//   2. conv x2   : Sb = bf16(seq_prev ++ seq_after) [65536][768]  (d_out scratch)
//   3. gemm1     : Pboth = relu(Sb @ Wt^T + bias) -> bf16         (ws, 96 MB)
//   4. gemm2     : sim[b] = Pp[b] @ Pa[b]^T -> fp32 d_out
//
// GEMM: round-5 proven 32x32x16 skeleton (256x256 tile, BK=64, 8 waves 2Mx4N,
// double-buffered 128KB LDS, pre-swizzled global_load_lds staging, counted
// vmcnt, 2 barriers/K-tile) + NEW: one-cluster-ahead ds_reads with counted
// lgkmcnt(12) and double-buffered fragment sets S0/S1, so every ds_read's
// issue+latency hides under a 16-MFMA cluster (round 6 showed the drain-0
// schedule serializes reads vs MFMA -> MfmaUtil 25%).

typedef __attribute__((ext_vector_type(8)))  short bf16x8v;
typedef __attribute__((ext_vector_type(8)))  short s16x8;
typedef __attribute__((ext_vector_type(16))) float f32x16;
typedef __attribute__((ext_vector_type(4)))  float float4v;

__device__ __forceinline__ unsigned short f2bf(float f) {
  unsigned int u = __float_as_uint(f);
  u += 0x7fffu + ((u >> 16) & 1u);
  return (unsigned short)(u >> 16);
}

__device__ __forceinline__ void async_copy16(void* lds, const void* g) {
  __builtin_amdgcn_global_load_lds(
      (const __attribute__((address_space(1))) void*)g,
      (__attribute__((address_space(3))) void*)lds, 16, 0, 0);
}

// pinned barrier / waits: sched_barrier(0) stops hipcc moving reg-only MFMA
// or ds/vm ops across them (rule #18; round-4 insurance, kept).
#define BARF()   do { __builtin_amdgcn_sched_barrier(0);                 \
                      __builtin_amdgcn_s_barrier();                      \
                      __builtin_amdgcn_sched_barrier(0); } while (0)
#define WAITV8() do { asm volatile("s_waitcnt vmcnt(8)" ::: "memory");   \
                      __builtin_amdgcn_sched_barrier(0); } while (0)
#define WAITV0() do { asm volatile("s_waitcnt vmcnt(0)" ::: "memory");   \
                      __builtin_amdgcn_sched_barrier(0); } while (0)
#define LGKM12() do { asm volatile("s_waitcnt lgkmcnt(12)" ::: "memory");\
                      __builtin_amdgcn_sched_barrier(0); } while (0)
#define LGKM0()  do { asm volatile("s_waitcnt lgkmcnt(0)" ::: "memory"); \
                      __builtin_amdgcn_sched_barrier(0); } while (0)

// ---------------- W transpose + convert: Wt[n][k] = bf16(W[k][n]) ------------
__global__ void wt_kernel(const float* __restrict__ W, short* __restrict__ Wt) {
  int idx = blockIdx.x * 256 + threadIdx.x;   // n*768 + k
  int n = idx / 768;
  int k = idx - n * 768;
  Wt[idx] = (short)f2bf(W[k * 768 + n]);
}

// ---------------- fp32 -> bf16 conversion (vectorized 8/thread) --------------
__global__ void conv_kernel(const float* __restrict__ X, short* __restrict__ Y, int n8) {
  int stride = gridDim.x * blockDim.x;
  for (int i = blockIdx.x * blockDim.x + threadIdx.x; i < n8; i += stride) {
    const float4v* Xv = (const float4v*)X;
    float4v a = Xv[2 * i];
    float4v b = Xv[2 * i + 1];
    s16x8 o;
    o[0] = (short)f2bf(a[0]); o[1] = (short)f2bf(a[1]);
    o[2] = (short)f2bf(a[2]); o[3] = (short)f2bf(a[3]);
    o[4] = (short)f2bf(b[0]); o[5] = (short)f2bf(b[1]);
    o[6] = (short)f2bf(b[2]); o[7] = (short)f2bf(b[3]);
    ((s16x8*)Y)[i] = o;
  }
}

// ---------------- Pipelined 256x256 GEMM (C = A @ B^T), K=768 ----------------
// EPI 0: fp32 store   EPI 1: bias+relu -> bf16 store
template<int EPI>
__global__ __launch_bounds__(512, 2)
void gemm_pipe(const short* __restrict__ A, const short* __restrict__ B,
               const float* __restrict__ bias, void* __restrict__ Cout,
               int ldc, long long sA, long long sB, long long sC) {
  constexpr int BK = 64, KT = 12;             // K = 768
  __shared__ __align__(16) short lA[2][256 * BK];
  __shared__ __align__(16) short lB[2][256 * BK];

  const int tid  = threadIdx.x;
  const int lane = tid & 63;
  const int w    = tid >> 6;                  // 0..7
  const int wr   = w >> 2;                    // 0..1  (M half: 128 rows)
  const int wc   = w & 3;                     // 0..3  (N quarter: 64 cols)
  const int bz   = blockIdx.z;
  const int tm   = blockIdx.y * 256;
  const int tn   = blockIdx.x * 256;

  const short* Ab = A + (size_t)bz * sA + (size_t)tm * 768;
  const short* Bb = B + (size_t)bz * sB + (size_t)tn * 768;

  const int l31  = lane & 31;                 // fragment row (A) / col (B)
  const int khb  = (lane >> 5) * 16;          // byte offset of lane's k-half
  const int sx   = (lane & 7) << 4;           // XOR swizzle term (row&7==lane&7)
  const int arow = wr * 128 + l31;            // A row base for this lane
  const int brow = wc * 64 + l31;             // B row base for this lane

  // stage one K-tile (8 global_load_lds); macro locals underscore-prefixed
#define STAGE(buf, k0)                                                        \
  {                                                                           \
    _Pragma("unroll")                                                         \
    for (int _j = 0; _j < 4; ++_j) {                                          \
      int _c    = _j * 512 + tid;                                             \
      int _row  = _c >> 3;                                                    \
      int _colb = ((_c & 7) * 16) ^ ((_row & 7) << 4);                        \
      async_copy16((char*)lA[buf] + _j * 8192 + w * 1024,                     \
                   (const char*)(Ab + (size_t)_row * 768 + (k0)) + _colb);    \
      async_copy16((char*)lB[buf] + _j * 8192 + w * 1024,                     \
                   (const char*)(Bb + (size_t)_row * 768 + (k0)) + _colb);    \
    }                                                                         \
  }

  // issue 12 ds_read_b128 for one K-half (kk): 8 A-frags + 4 B-frags
#define LOAD_FRAGS(AF, BF, buf, kk)                                           \
  {                                                                           \
    const char* _bA = (const char*)lA[buf];                                   \
    const char* _bB = (const char*)lB[buf];                                   \
    _Pragma("unroll")                                                         \
    for (int _ks = 0; _ks < 2; ++_ks) {                                       \
      const int _kx = ((kk) * 64 + _ks * 32 + khb) ^ sx;                      \
      _Pragma("unroll")                                                       \
      for (int _mt = 0; _mt < 4; ++_mt)                                       \
        AF[_mt][_ks] = *(const bf16x8v*)(_bA + (arow + _mt * 32) * 128 + _kx);\
      _Pragma("unroll")                                                       \
      for (int _nt = 0; _nt < 2; ++_nt)                                       \
        BF[_nt][_ks] = *(const bf16x8v*)(_bB + (brow + _nt * 32) * 128 + _kx);\
    }                                                                         \
  }

  // 16 MFMA cluster consuming one frag set
#define MFMA_PHASE(AF, BF)                                                    \
  {                                                                           \
    __builtin_amdgcn_s_setprio(1);                                            \
    _Pragma("unroll")                                                         \
    for (int _ks = 0; _ks < 2; ++_ks)                                         \
      _Pragma("unroll")                                                       \
      for (int _mt = 0; _mt < 4; ++_mt)                                       \
        _Pragma("unroll")                                                     \
        for (int _nt = 0; _nt < 2; ++_nt)                                     \
          acc[_mt][_nt] = __builtin_amdgcn_mfma_f32_32x32x16_bf16(            \
              AF[_mt][_ks], BF[_nt][_ks], acc[_mt][_nt], 0, 0, 0);            \
    __builtin_amdgcn_s_setprio(0);                                            \
  }

  f32x16 acc[4][2] = {};
  bf16x8v afA[4][2], bgA[2][2];   // frag set S0
  bf16x8v afB[4][2], bgB[2][2];   // frag set S1

  // prologue: stage tiles 0,1; sync tile0; issue S0 = (tile0, kk0)
  STAGE(0, 0);
  STAGE(1, BK);
  WAITV8();
  BARF();
  LOAD_FRAGS(afA, bgA, 0, 0);                 // DS out: 12

  for (int kt = 0; kt < KT; ++kt) {
    const int cur = kt & 1;
    const int nxt = cur ^ 1;
    // issue kk1 reads, then compute kk0 under their latency
    LOAD_FRAGS(afB, bgB, cur, 1);             // DS out: 24
    LGKM12();                                 // S0 ready (S1 in flight)
    MFMA_PHASE(afA, bgA);
    LGKM0();                                  // S1 ready; all buf[cur] reads done
    BARF();                                   // WAR fence: buf[cur] free
    if (kt + 2 < KT) STAGE(cur, (kt + 2) * BK);
    if (kt + 1 < KT) {
      if (kt + 2 < KT) { WAITV8(); } else { WAITV0(); }  // tile kt+1 landed
      BARF();                                 // landed for everyone
      LOAD_FRAGS(afA, bgA, nxt, 0);           // DS out: 12 (next tile kk0)
    }
    MFMA_PHASE(afB, bgB);                     // kk1 under next-tile read latency
  }

  // epilogue: C/D layout col=lane&31, row=(reg&3)+8*(reg>>2)+4*(lane>>5)
#pragma unroll
  for (int mt = 0; mt < 4; ++mt) {
    int rowb = tm + wr * 128 + mt * 32 + 4 * (lane >> 5);
#pragma unroll
    for (int nt = 0; nt < 2; ++nt) {
      int col = tn + wc * 64 + nt * 32 + l31;
      if (EPI == 0) {
        float* C = (float*)Cout + (size_t)bz * sC;
#pragma unroll
        for (int reg = 0; reg < 16; ++reg) {
          int row = rowb + (reg & 3) + 8 * (reg >> 2);
          C[(size_t)row * ldc + col] = acc[mt][nt][reg];
        }
      } else {
        short* C = (short*)Cout + (size_t)bz * sC;
        float bv = bias[col];
#pragma unroll
        for (int reg = 0; reg < 16; ++reg) {
          int row = rowb + (reg & 3) + 8 * (reg >> 2);
          float v = fmaxf(acc[mt][nt][reg] + bv, 0.0f);
          C[(size_t)row * ldc + col] = (short)f2bf(v);
        }
      }
    }
  }
#undef STAGE
#undef LOAD_FRAGS
#undef MFMA_PHASE
}

extern "C" void kernel_launch(void* const* d_in, const int* in_sizes, int n_in,
                              void* d_out, int out_size, void* d_ws, size_t ws_size,
                              hipStream_t stream) {
  const float* seq_prev  = (const float*)d_in[0];  // [16][2048][768]
  const float* seq_after = (const float*)d_in[1];  // [16][2048][768]
  const float* W         = (const float*)d_in[2];  // [768][768] (in,out)
  const float* bias      = (const float*)d_in[3];  // [768]
  float* out             = (float*)d_out;          // [16][2048][2048] fp32

  char* ws   = (char*)d_ws;
  short* Wt  = (short*)ws;                         // 768*768*2   = 1179648 B
  short* Pb  = (short*)(ws + 1179648);             // 65536*768*2 = 100663296 B
  short* Sb  = (short*)d_out;                      // scratch in d_out (96 MB)

  constexpr int NSEQ = 16 * 2048 * 768;
  constexpr int N8   = NSEQ / 8;

  // 1. W transpose + convert
  wt_kernel<<<768 * 768 / 256, 256, 0, stream>>>(W, Wt);

  // 2. convert both sequences to bf16 (into d_out scratch)
  conv_kernel<<<2048, 256, 0, stream>>>(seq_prev,  Sb,        N8);
  conv_kernel<<<2048, 256, 0, stream>>>(seq_after, Sb + NSEQ, N8);

  // 3. feed-forward + relu, both seqs at once: M=65536, N=768
  dim3 g1(3, 256, 1);
  gemm_pipe<1><<<g1, 512, 0, stream>>>(Sb, Wt, bias, Pb, 768, 0, 0, 0);

  // 4. batched similarity: sim[b] = Pp[b] @ Pa[b]^T  (M=N=2048 per batch)
  dim3 g2(8, 8, 16);
  gemm_pipe<0><<<g2, 512, 0, stream>>>(Pb, Pb + NSEQ, nullptr, out,
                                       2048, 2048 * 768, 2048 * 768,
                                       2048LL * 2048);
}

// Round 8
// 289.712 us; speedup vs baseline: 1.1235x; 1.0795x over previous
//
#include <hip/hip_runtime.h>
#include <hip/hip_bf16.h>

// sim[b,l,m] = sum_d relu(prev@W+b)[b,l,d] * relu(after@W+b)[b,m,d]
// bz=16, L=2048, d=768.
//
// Pipeline:
//   1. wt_kernel : Wt[n][k] = bf16(W[k][n])                   (ws, 1.2 MB)
//   2. gemm_ff   : Pb = relu(bf16(seq) @ Wt^T + bias) -> bf16 (ws, 96 MB)
//                  fp32->bf16 conversion FUSED into A-staging (conv pass gone)
//   3. gemm2     : sim[b] = Pp[b] @ Pa[b]^T -> fp32 d_out     (round-5 kernel,
//                  byte-identical: proven fastest at 304 us total)

typedef __attribute__((ext_vector_type(8)))  short bf16x8v;
typedef __attribute__((ext_vector_type(8)))  short s16x8;
typedef __attribute__((ext_vector_type(16))) float f32x16;
typedef __attribute__((ext_vector_type(4)))  float float4v;

__device__ __forceinline__ unsigned short f2bf(float f) {
  unsigned int u = __float_as_uint(f);
  u += 0x7fffu + ((u >> 16) & 1u);
  return (unsigned short)(u >> 16);
}

__device__ __forceinline__ void async_copy16(void* lds, const void* g) {
  __builtin_amdgcn_global_load_lds(
      (const __attribute__((address_space(1))) void*)g,
      (__attribute__((address_space(3))) void*)lds, 16, 0, 0);
}

// round-5 macro set (gemm2, proven)
#define BAR()    asm volatile("s_barrier" ::: "memory")
#define WAITV8() asm volatile("s_waitcnt vmcnt(8)" ::: "memory")
#define WAITV0() asm volatile("s_waitcnt vmcnt(0)" ::: "memory")
#define WAITL()  do { asm volatile("s_waitcnt lgkmcnt(0)" ::: "memory"); \
                      __builtin_amdgcn_sched_barrier(0); } while (0)
// pinned variants (gemm_ff)
#define FBARF()   do { __builtin_amdgcn_sched_barrier(0);                 \
                       __builtin_amdgcn_s_barrier();                      \
                       __builtin_amdgcn_sched_barrier(0); } while (0)
#define FWAITV(n) do { asm volatile("s_waitcnt vmcnt(" #n ")" ::: "memory"); \
                       __builtin_amdgcn_sched_barrier(0); } while (0)
#define FLGKM0()  do { asm volatile("s_waitcnt lgkmcnt(0)" ::: "memory");  \
                       __builtin_amdgcn_sched_barrier(0); } while (0)

// ---------------- W transpose + convert: Wt[n][k] = bf16(W[k][n]) ------------
__global__ void wt_kernel(const float* __restrict__ W, short* __restrict__ Wt) {
  int idx = blockIdx.x * 256 + threadIdx.x;   // n*768 + k
  int n = idx / 768;
  int k = idx - n * 768;
  Wt[idx] = (short)f2bf(W[k * 768 + n]);
}

// ======== gemm_ff: Pb = relu(bf16(seq) @ Wt^T + bias), conversion fused ======
// A: fp32 [32768][768] per seq (selected by blockIdx.y); B: Wt bf16 [768][768].
// 256x256 tile, BK=64, 8 waves (2Mx4N), dbuf 128KB LDS, swizzled layout.
// A path: global fp32 -> regs -> cvt -> swizzled ds_write (pipelined 2 ahead).
// B path: global_load_lds with pre-swizzled source.
__global__ __launch_bounds__(512, 2)
void gemm_ff(const float* __restrict__ Sprev, const float* __restrict__ Safter,
             const short* __restrict__ Wt, const float* __restrict__ bias,
             short* __restrict__ Out) {
  constexpr int BK = 64, KT = 12;             // K = 768
  __shared__ __align__(16) short lA[2][256 * BK];
  __shared__ __align__(16) short lB[2][256 * BK];

  const int tid  = threadIdx.x;
  const int lane = tid & 63;
  const int w    = tid >> 6;
  const int wr   = w >> 2;                    // 0..1 (M half)
  const int wc   = w & 3;                     // 0..3 (N quarter)
  const int by   = blockIdx.y;                // 0..255
  const int tn   = blockIdx.x * 256;          // 0,256,512

  const float* Af = (by < 128 ? Sprev : Safter) + (size_t)((by & 127) * 256) * 768;
  const int    tm = by * 256;                 // global output row base

  const int l31  = lane & 31;
  const int khb  = (lane >> 5) * 16;
  const int sx   = (lane & 7) << 4;
  const int arow = wr * 128 + l31;
  const int brow = wc * 64 + l31;

#define FF_LOAD_A(k0)                                                         \
  {                                                                           \
    _Pragma("unroll")                                                         \
    for (int _q = 0; _q < 4; ++_q) {                                          \
      int _seg = _q * 512 + tid;                                              \
      int _row = _seg >> 3;                                                   \
      const float* _g = Af + (size_t)_row * 768 + (k0) + (_seg & 7) * 8;      \
      ar[2 * _q]     = *(const float4v*)_g;                                   \
      ar[2 * _q + 1] = *(const float4v*)(_g + 4);                             \
    }                                                                         \
  }

#define FF_CVT_WRITE(buf)                                                     \
  {                                                                           \
    _Pragma("unroll")                                                         \
    for (int _q = 0; _q < 4; ++_q) {                                          \
      int _seg = _q * 512 + tid;                                              \
      int _row = _seg >> 3;                                                   \
      int _cb  = ((_seg & 7) * 16) ^ ((_row & 7) << 4);                       \
      s16x8 _o;                                                               \
      _o[0] = (short)f2bf(ar[2 * _q][0]);     _o[1] = (short)f2bf(ar[2 * _q][1]); \
      _o[2] = (short)f2bf(ar[2 * _q][2]);     _o[3] = (short)f2bf(ar[2 * _q][3]); \
      _o[4] = (short)f2bf(ar[2 * _q + 1][0]); _o[5] = (short)f2bf(ar[2 * _q + 1][1]); \
      _o[6] = (short)f2bf(ar[2 * _q + 1][2]); _o[7] = (short)f2bf(ar[2 * _q + 1][3]); \
      *(s16x8*)((char*)lA[buf] + _row * 128 + _cb) = _o;                      \
    }                                                                         \
  }

#define FF_STAGE_B(buf, k0)                                                   \
  {                                                                           \
    _Pragma("unroll")                                                         \
    for (int _j = 0; _j < 4; ++_j) {                                          \
      int _c   = _j * 512 + tid;                                              \
      int _row = _c >> 3;                                                     \
      int _cb  = ((_c & 7) * 16) ^ ((_row & 7) << 4);                         \
      async_copy16((char*)lB[buf] + _j * 8192 + w * 1024,                     \
                   (const char*)(Wt + (size_t)(tn + _row) * 768 + (k0)) + _cb); \
    }                                                                         \
  }

#define FF_FRAGS(buf, kk)                                                     \
  {                                                                           \
    const char* _bA = (const char*)lA[buf];                                   \
    const char* _bB = (const char*)lB[buf];                                   \
    _Pragma("unroll")                                                         \
    for (int _ks = 0; _ks < 2; ++_ks) {                                       \
      const int _kx = ((kk) * 64 + _ks * 32 + khb) ^ sx;                      \
      _Pragma("unroll")                                                       \
      for (int _mt = 0; _mt < 4; ++_mt)                                       \
        af[_mt][_ks] = *(const bf16x8v*)(_bA + (arow + _mt * 32) * 128 + _kx);\
      _Pragma("unroll")                                                       \
      for (int _nt = 0; _nt < 2; ++_nt)                                       \
        bg[_nt][_ks] = *(const bf16x8v*)(_bB + (brow + _nt * 32) * 128 + _kx);\
    }                                                                         \
  }

#define FF_MFMA()                                                             \
  {                                                                           \
    __builtin_amdgcn_s_setprio(1);                                            \
    _Pragma("unroll")                                                         \
    for (int _ks = 0; _ks < 2; ++_ks)                                         \
      _Pragma("unroll")                                                       \
      for (int _mt = 0; _mt < 4; ++_mt)                                       \
        _Pragma("unroll")                                                     \
        for (int _nt = 0; _nt < 2; ++_nt)                                     \
          acc[_mt][_nt] = __builtin_amdgcn_mfma_f32_32x32x16_bf16(            \
              af[_mt][_ks], bg[_nt][_ks], acc[_mt][_nt], 0, 0, 0);            \
    __builtin_amdgcn_s_setprio(0);                                            \
  }

  f32x16 acc[4][2] = {};
  bf16x8v af[4][2], bg[2][2];
  float4v ar[8];

  // prologue: A(0) -> regs -> lA[0]; A(1) -> regs; B(0),B(1) staged.
  FF_LOAD_A(0);                               // vm: A0=8
  FWAITV(0);
  FF_CVT_WRITE(0);
  FF_LOAD_A(BK);                              // vm: A1=8
  FF_STAGE_B(0, 0);                           // vm: +B0=4
  FF_STAGE_B(1, BK);                          // vm: +B1=4  (out: 16)
  FLGKM0();                                   // own lA[0] writes done
  FWAITV(4);                                  // retires A1+B0 (oldest 12): B0 landed
  FBARF();                                    // tile0 ready for everyone

  for (int kt = 0; kt < KT; ++kt) {
    const int cur = kt & 1, nxt = cur ^ 1;
    FF_FRAGS(cur, 0);                         // 12 ds_read
    if (kt + 1 < KT) {
      FWAITV(4);                              // A(kt+1) (oldest 8) landed
      FF_CVT_WRITE(nxt);                      // 4 ds_write -> lA[nxt]
    }
    FLGKM0();                                 // frags + writes done
    FF_MFMA();                                // kk0
    if (kt + 2 < KT) FF_LOAD_A((kt + 2) * BK);  // 8 vm (regs free post-cvt)
    FF_FRAGS(cur, 1);                         // 12 ds_read
    FLGKM0();                                 // all reads of buf[cur] done
    if (kt + 1 < KT) {
      if (kt + 2 < KT) { FWAITV(8); }         // B(kt+1) (oldest 4) landed
      else             { FWAITV(0); }         // tail drain
      FBARF();                                // tile kt+1 ready; buf[cur] free
      if (kt + 2 < KT) FF_STAGE_B(cur, (kt + 2) * BK);  // 4 vm
    }
    FF_MFMA();                                // kk1
  }

  // epilogue: bias+relu -> bf16; C/D: col=lane&31, row=(reg&3)+8*(reg>>2)+4*(lane>>5)
#pragma unroll
  for (int mt = 0; mt < 4; ++mt) {
    int rowb = tm + wr * 128 + mt * 32 + 4 * (lane >> 5);
#pragma unroll
    for (int nt = 0; nt < 2; ++nt) {
      int col = tn + wc * 64 + nt * 32 + l31;
      float bv = bias[col];
#pragma unroll
      for (int reg = 0; reg < 16; ++reg) {
        int row = rowb + (reg & 3) + 8 * (reg >> 2);
        float v = fmaxf(acc[mt][nt][reg] + bv, 0.0f);
        Out[(size_t)row * 768 + col] = (short)f2bf(v);
      }
    }
  }
#undef FF_LOAD_A
#undef FF_CVT_WRITE
#undef FF_STAGE_B
#undef FF_FRAGS
#undef FF_MFMA
}

// ======== gemm2: round-5 kernel, byte-identical (proven fastest) =============
template<int EPI>
__global__ __launch_bounds__(512, 2)
void gemm_pipe(const short* __restrict__ A, const short* __restrict__ B,
               const float* __restrict__ bias, void* __restrict__ Cout,
               int ldc, long long sA, long long sB, long long sC) {
  constexpr int BK = 64, KT = 12;             // K = 768
  __shared__ __align__(16) short lA[2][256 * BK];
  __shared__ __align__(16) short lB[2][256 * BK];

  const int tid  = threadIdx.x;
  const int lane = tid & 63;
  const int w    = tid >> 6;                  // 0..7
  const int wr   = w >> 2;                    // 0..1  (M half: 128 rows)
  const int wc   = w & 3;                     // 0..3  (N quarter: 64 cols)
  const int bz   = blockIdx.z;
  const int tm   = blockIdx.y * 256;
  const int tn   = blockIdx.x * 256;

  const short* Ab = A + (size_t)bz * sA + (size_t)tm * 768;
  const short* Bb = B + (size_t)bz * sB + (size_t)tn * 768;

  const int l31  = lane & 31;                 // fragment row (A) / col (B)
  const int khb  = (lane >> 5) * 16;          // byte offset of lane's k-half
  const int sx   = (lane & 7) << 4;           // XOR swizzle term
  const int arow = wr * 128 + l31;
  const int brow = wc * 64 + l31;

#define STAGE(buf, k0)                                                        \
  {                                                                           \
    _Pragma("unroll")                                                         \
    for (int _j = 0; _j < 4; ++_j) {                                          \
      int _c    = _j * 512 + tid;                                             \
      int _row  = _c >> 3;                                                    \
      int _colb = ((_c & 7) * 16) ^ ((_row & 7) << 4);                        \
      async_copy16((char*)lA[buf] + _j * 8192 + w * 1024,                     \
                   (const char*)(Ab + (size_t)_row * 768 + (k0)) + _colb);    \
      async_copy16((char*)lB[buf] + _j * 8192 + w * 1024,                     \
                   (const char*)(Bb + (size_t)_row * 768 + (k0)) + _colb);    \
    }                                                                         \
  }

#define LOAD_FRAGS(buf, kk)                                                   \
  {                                                                           \
    const char* _bA = (const char*)lA[buf];                                   \
    const char* _bB = (const char*)lB[buf];                                   \
    _Pragma("unroll")                                                         \
    for (int _ks = 0; _ks < 2; ++_ks) {                                       \
      const int _kx = ((kk) * 64 + _ks * 32 + khb) ^ sx;                      \
      _Pragma("unroll")                                                       \
      for (int _mt = 0; _mt < 4; ++_mt)                                       \
        af[_mt][_ks] = *(const bf16x8v*)(_bA + (arow + _mt * 32) * 128 + _kx);\
      _Pragma("unroll")                                                       \
      for (int _nt = 0; _nt < 2; ++_nt)                                       \
        bg[_nt][_ks] = *(const bf16x8v*)(_bB + (brow + _nt * 32) * 128 + _kx);\
    }                                                                         \
  }

#define MFMA_PHASE()                                                          \
  {                                                                           \
    __builtin_amdgcn_s_setprio(1);                                            \
    _Pragma("unroll")                                                         \
    for (int _ks = 0; _ks < 2; ++_ks)                                         \
      _Pragma("unroll")                                                       \
      for (int _mt = 0; _mt < 4; ++_mt)                                       \
        _Pragma("unroll")                                                     \
        for (int _nt = 0; _nt < 2; ++_nt)                                     \
          acc[_mt][_nt] = __builtin_amdgcn_mfma_f32_32x32x16_bf16(            \
              af[_mt][_ks], bg[_nt][_ks], acc[_mt][_nt], 0, 0, 0);            \
    __builtin_amdgcn_s_setprio(0);                                            \
  }

  f32x16 acc[4][2] = {};
  bf16x8v af[4][2], bg[2][2];

  STAGE(0, 0);
  STAGE(1, BK);

  int cur = 0;
  for (int kt = 0; kt < KT; ++kt) {
    if (kt < KT - 1) { WAITV8(); } else { WAITV0(); }
    BAR();

    LOAD_FRAGS(cur, 0);
    WAITL();
    MFMA_PHASE();

    LOAD_FRAGS(cur, 1);
    WAITL();
    BAR();
    if (kt < KT - 2) STAGE(cur, (kt + 2) * BK);
    MFMA_PHASE();

    cur ^= 1;
  }

#pragma unroll
  for (int mt = 0; mt < 4; ++mt) {
    int rowb = tm + wr * 128 + mt * 32 + 4 * (lane >> 5);
#pragma unroll
    for (int nt = 0; nt < 2; ++nt) {
      int col = tn + wc * 64 + nt * 32 + l31;
      if (EPI == 0) {
        float* C = (float*)Cout + (size_t)bz * sC;
#pragma unroll
        for (int reg = 0; reg < 16; ++reg) {
          int row = rowb + (reg & 3) + 8 * (reg >> 2);
          C[(size_t)row * ldc + col] = acc[mt][nt][reg];
        }
      } else {
        short* C = (short*)Cout + (size_t)bz * sC;
        float bv = bias[col];
#pragma unroll
        for (int reg = 0; reg < 16; ++reg) {
          int row = rowb + (reg & 3) + 8 * (reg >> 2);
          float v = fmaxf(acc[mt][nt][reg] + bv, 0.0f);
          C[(size_t)row * ldc + col] = (short)f2bf(v);
        }
      }
    }
  }
#undef STAGE
#undef LOAD_FRAGS
#undef MFMA_PHASE
}

extern "C" void kernel_launch(void* const* d_in, const int* in_sizes, int n_in,
                              void* d_out, int out_size, void* d_ws, size_t ws_size,
                              hipStream_t stream) {
  const float* seq_prev  = (const float*)d_in[0];  // [16][2048][768]
  const float* seq_after = (const float*)d_in[1];  // [16][2048][768]
  const float* W         = (const float*)d_in[2];  // [768][768] (in,out)
  const float* bias      = (const float*)d_in[3];  // [768]
  float* out             = (float*)d_out;          // [16][2048][2048] fp32

  char* ws   = (char*)d_ws;
  short* Wt  = (short*)ws;                         // 768*768*2   = 1179648 B
  short* Pb  = (short*)(ws + 1179648);             // 65536*768*2 = 100663296 B

  constexpr int NSEQ = 16 * 2048 * 768;

  // 1. W transpose + convert
  wt_kernel<<<768 * 768 / 256, 256, 0, stream>>>(W, Wt);

  // 2. feed-forward + relu, conversion fused: M=65536 (prev then after), N=768
  dim3 g1(3, 256, 1);
  gemm_ff<<<g1, 512, 0, stream>>>(seq_prev, seq_after, Wt, bias, Pb);

  // 3. batched similarity: sim[b] = Pp[b] @ Pa[b]^T  (M=N=2048 per batch)
  dim3 g2(8, 8, 16);
  gemm_pipe<0><<<g2, 512, 0, stream>>>(Pb, Pb + NSEQ, nullptr, out,
                                       2048, 2048 * 768, 2048 * 768,
                                       2048LL * 2048);
}

// Round 9
// 271.160 us; speedup vs baseline: 1.2003x; 1.0684x over previous
//
#include <hip/hip_runtime.h>
#include <hip/hip_bf16.h>

// sim[b,l,m] = sum_d relu(prev@W+b)[b,l,d] * relu(after@W+b)[b,m,d]
// bz=16, L=2048, d=768.
//
// Pipeline:
//   1. wt_kernel : Wt[n][k] = bf16(W[k][n])                   (ws, 1.2 MB)
//   2. gemm_ff   : Pb = relu(bf16(seq) @ Wt^T + bias) -> bf16 (ws, 96 MB)
//   3. gemm_sim  : sim[b] = Pp[b] @ Pa[b]^T -> fp32 d_out
//
// NEW vs round 8: XCD-chunked blockIdx swizzle (T1) on both GEMMs so blocks
// sharing an A-panel run on the same XCD's L2:
//   gemm_ff : 768 blocks, virt=(bid%8)*96+bid/8 ; by=virt/3, bx=virt%3
//             -> the 3 N-tile siblings of one M-tile are XCD-consecutive.
//   gemm_sim: 1024 blocks, virt=(bid%8)*128+bid/8; bz=virt>>6, by=(virt>>3)&7,
//             bx=virt&7 -> one x-row (A-panel + 8 B-panels = 3.4MB) per XCD.

typedef __attribute__((ext_vector_type(8)))  short bf16x8v;
typedef __attribute__((ext_vector_type(8)))  short s16x8;
typedef __attribute__((ext_vector_type(16))) float f32x16;
typedef __attribute__((ext_vector_type(4)))  float float4v;

__device__ __forceinline__ unsigned short f2bf(float f) {
  unsigned int u = __float_as_uint(f);
  u += 0x7fffu + ((u >> 16) & 1u);
  return (unsigned short)(u >> 16);
}

__device__ __forceinline__ void async_copy16(void* lds, const void* g) {
  __builtin_amdgcn_global_load_lds(
      (const __attribute__((address_space(1))) void*)g,
      (__attribute__((address_space(3))) void*)lds, 16, 0, 0);
}

// proven macro set (round-5 skeleton)
#define BAR()    asm volatile("s_barrier" ::: "memory")
#define WAITV8() asm volatile("s_waitcnt vmcnt(8)" ::: "memory")
#define WAITV0() asm volatile("s_waitcnt vmcnt(0)" ::: "memory")
#define WAITL()  do { asm volatile("s_waitcnt lgkmcnt(0)" ::: "memory"); \
                      __builtin_amdgcn_sched_barrier(0); } while (0)
// pinned variants (gemm_ff)
#define FBARF()   do { __builtin_amdgcn_sched_barrier(0);                 \
                       __builtin_amdgcn_s_barrier();                      \
                       __builtin_amdgcn_sched_barrier(0); } while (0)
#define FWAITV(n) do { asm volatile("s_waitcnt vmcnt(" #n ")" ::: "memory"); \
                       __builtin_amdgcn_sched_barrier(0); } while (0)
#define FLGKM0()  do { asm volatile("s_waitcnt lgkmcnt(0)" ::: "memory");  \
                       __builtin_amdgcn_sched_barrier(0); } while (0)

// ---------------- W transpose + convert: Wt[n][k] = bf16(W[k][n]) ------------
__global__ void wt_kernel(const float* __restrict__ W, short* __restrict__ Wt) {
  int idx = blockIdx.x * 256 + threadIdx.x;   // n*768 + k
  int n = idx / 768;
  int k = idx - n * 768;
  Wt[idx] = (short)f2bf(W[k * 768 + n]);
}

// ======== gemm_ff: Pb = relu(bf16(seq) @ Wt^T + bias), conversion fused ======
__global__ __launch_bounds__(512, 2)
void gemm_ff(const float* __restrict__ Sprev, const float* __restrict__ Safter,
             const short* __restrict__ Wt, const float* __restrict__ bias,
             short* __restrict__ Out) {
  constexpr int BK = 64, KT = 12;             // K = 768
  __shared__ __align__(16) short lA[2][256 * BK];
  __shared__ __align__(16) short lB[2][256 * BK];

  // T1: XCD-chunked swizzle (768 = 8 * 96, bijective). Siblings bx=0,1,2 of
  // one by are consecutive in virt -> same XCD -> share the A-panel in L2.
  const int bid  = blockIdx.x;                // 0..767
  const int virt = (bid & 7) * 96 + (bid >> 3);
  const int by   = virt / 3;                  // 0..255 (M-tile)
  const int bx   = virt - by * 3;             // 0..2   (N-tile)

  const int tid  = threadIdx.x;
  const int lane = tid & 63;
  const int w    = tid >> 6;
  const int wr   = w >> 2;                    // 0..1 (M half)
  const int wc   = w & 3;                     // 0..3 (N quarter)
  const int tn   = bx * 256;                  // 0,256,512

  const float* Af = (by < 128 ? Sprev : Safter) + (size_t)((by & 127) * 256) * 768;
  const int    tm = by * 256;                 // global output row base

  const int l31  = lane & 31;
  const int khb  = (lane >> 5) * 16;
  const int sx   = (lane & 7) << 4;
  const int arow = wr * 128 + l31;
  const int brow = wc * 64 + l31;

#define FF_LOAD_A(k0)                                                         \
  {                                                                           \
    _Pragma("unroll")                                                         \
    for (int _q = 0; _q < 4; ++_q) {                                          \
      int _seg = _q * 512 + tid;                                              \
      int _row = _seg >> 3;                                                   \
      const float* _g = Af + (size_t)_row * 768 + (k0) + (_seg & 7) * 8;      \
      ar[2 * _q]     = *(const float4v*)_g;                                   \
      ar[2 * _q + 1] = *(const float4v*)(_g + 4);                             \
    }                                                                         \
  }

#define FF_CVT_WRITE(buf)                                                     \
  {                                                                           \
    _Pragma("unroll")                                                         \
    for (int _q = 0; _q < 4; ++_q) {                                          \
      int _seg = _q * 512 + tid;                                              \
      int _row = _seg >> 3;                                                   \
      int _cb  = ((_seg & 7) * 16) ^ ((_row & 7) << 4);                       \
      s16x8 _o;                                                               \
      _o[0] = (short)f2bf(ar[2 * _q][0]);     _o[1] = (short)f2bf(ar[2 * _q][1]); \
      _o[2] = (short)f2bf(ar[2 * _q][2]);     _o[3] = (short)f2bf(ar[2 * _q][3]); \
      _o[4] = (short)f2bf(ar[2 * _q + 1][0]); _o[5] = (short)f2bf(ar[2 * _q + 1][1]); \
      _o[6] = (short)f2bf(ar[2 * _q + 1][2]); _o[7] = (short)f2bf(ar[2 * _q + 1][3]); \
      *(s16x8*)((char*)lA[buf] + _row * 128 + _cb) = _o;                      \
    }                                                                         \
  }

#define FF_STAGE_B(buf, k0)                                                   \
  {                                                                           \
    _Pragma("unroll")                                                         \
    for (int _j = 0; _j < 4; ++_j) {                                          \
      int _c   = _j * 512 + tid;                                              \
      int _row = _c >> 3;                                                     \
      int _cb  = ((_c & 7) * 16) ^ ((_row & 7) << 4);                         \
      async_copy16((char*)lB[buf] + _j * 8192 + w * 1024,                     \
                   (const char*)(Wt + (size_t)(tn + _row) * 768 + (k0)) + _cb); \
    }                                                                         \
  }

#define FF_FRAGS(buf, kk)                                                     \
  {                                                                           \
    const char* _bA = (const char*)lA[buf];                                   \
    const char* _bB = (const char*)lB[buf];                                   \
    _Pragma("unroll")                                                         \
    for (int _ks = 0; _ks < 2; ++_ks) {                                       \
      const int _kx = ((kk) * 64 + _ks * 32 + khb) ^ sx;                      \
      _Pragma("unroll")                                                       \
      for (int _mt = 0; _mt < 4; ++_mt)                                       \
        af[_mt][_ks] = *(const bf16x8v*)(_bA + (arow + _mt * 32) * 128 + _kx);\
      _Pragma("unroll")                                                       \
      for (int _nt = 0; _nt < 2; ++_nt)                                       \
        bg[_nt][_ks] = *(const bf16x8v*)(_bB + (brow + _nt * 32) * 128 + _kx);\
    }                                                                         \
  }

#define FF_MFMA()                                                             \
  {                                                                           \
    __builtin_amdgcn_s_setprio(1);                                            \
    _Pragma("unroll")                                                         \
    for (int _ks = 0; _ks < 2; ++_ks)                                         \
      _Pragma("unroll")                                                       \
      for (int _mt = 0; _mt < 4; ++_mt)                                       \
        _Pragma("unroll")                                                     \
        for (int _nt = 0; _nt < 2; ++_nt)                                     \
          acc[_mt][_nt] = __builtin_amdgcn_mfma_f32_32x32x16_bf16(            \
              af[_mt][_ks], bg[_nt][_ks], acc[_mt][_nt], 0, 0, 0);            \
    __builtin_amdgcn_s_setprio(0);                                            \
  }

  f32x16 acc[4][2] = {};
  bf16x8v af[4][2], bg[2][2];
  float4v ar[8];

  // prologue: A(0) -> regs -> lA[0]; A(1) -> regs; B(0),B(1) staged.
  FF_LOAD_A(0);                               // vm: A0=8
  FWAITV(0);
  FF_CVT_WRITE(0);
  FF_LOAD_A(BK);                              // vm: A1=8
  FF_STAGE_B(0, 0);                           // vm: +B0=4
  FF_STAGE_B(1, BK);                          // vm: +B1=4  (out: 16)
  FLGKM0();                                   // own lA[0] writes done
  FWAITV(4);                                  // retires A1+B0: B0 landed
  FBARF();                                    // tile0 ready for everyone

  for (int kt = 0; kt < KT; ++kt) {
    const int cur = kt & 1, nxt = cur ^ 1;
    FF_FRAGS(cur, 0);                         // 12 ds_read
    if (kt + 1 < KT) {
      FWAITV(4);                              // A(kt+1) landed
      FF_CVT_WRITE(nxt);                      // 4 ds_write -> lA[nxt]
    }
    FLGKM0();                                 // frags + writes done
    FF_MFMA();                                // kk0
    if (kt + 2 < KT) FF_LOAD_A((kt + 2) * BK);  // 8 vm
    FF_FRAGS(cur, 1);                         // 12 ds_read
    FLGKM0();                                 // all reads of buf[cur] done
    if (kt + 1 < KT) {
      if (kt + 2 < KT) { FWAITV(8); }         // B(kt+1) landed
      else             { FWAITV(0); }         // tail drain
      FBARF();                                // tile kt+1 ready; buf[cur] free
      if (kt + 2 < KT) FF_STAGE_B(cur, (kt + 2) * BK);
    }
    FF_MFMA();                                // kk1
  }

  // epilogue: bias+relu -> bf16
#pragma unroll
  for (int mt = 0; mt < 4; ++mt) {
    int rowb = tm + wr * 128 + mt * 32 + 4 * (lane >> 5);
#pragma unroll
    for (int nt = 0; nt < 2; ++nt) {
      int col = tn + wc * 64 + nt * 32 + l31;
      float bv = bias[col];
#pragma unroll
      for (int reg = 0; reg < 16; ++reg) {
        int row = rowb + (reg & 3) + 8 * (reg >> 2);
        float v = fmaxf(acc[mt][nt][reg] + bv, 0.0f);
        Out[(size_t)row * 768 + col] = (short)f2bf(v);
      }
    }
  }
#undef FF_LOAD_A
#undef FF_CVT_WRITE
#undef FF_STAGE_B
#undef FF_FRAGS
#undef FF_MFMA
}

// ======== gemm_sim: sim[b] = Pp[b] @ Pa[b]^T (round-5 kernel + T1) ==========
__global__ __launch_bounds__(512, 2)
void gemm_sim(const short* __restrict__ A, const short* __restrict__ B,
              float* __restrict__ C) {
  constexpr int BK = 64, KT = 12, LD = 2048;  // K = 768
  __shared__ __align__(16) short lA[2][256 * BK];
  __shared__ __align__(16) short lB[2][256 * BK];

  // T1: XCD-chunked swizzle (1024 = 8 * 128, bijective). One x-row (8 blocks
  // sharing the A-panel, 8 distinct B-panels = 3.4 MB) per XCD chunk.
  const int bid  = blockIdx.x;                // 0..1023
  const int virt = (bid & 7) * 128 + (bid >> 3);
  const int bz   = virt >> 6;                 // 0..15 batch
  const int by   = (virt >> 3) & 7;           // M-tile
  const int bx   = virt & 7;                  // N-tile

  const int tid  = threadIdx.x;
  const int lane = tid & 63;
  const int w    = tid >> 6;
  const int wr   = w >> 2;
  const int wc   = w & 3;
  const int tm   = by * 256;
  const int tn   = bx * 256;

  const short* Ab = A + (size_t)bz * LD * 768 + (size_t)tm * 768;
  const short* Bb = B + (size_t)bz * LD * 768 + (size_t)tn * 768;

  const int l31  = lane & 31;
  const int khb  = (lane >> 5) * 16;
  const int sx   = (lane & 7) << 4;
  const int arow = wr * 128 + l31;
  const int brow = wc * 64 + l31;

#define STAGE(buf, k0)                                                        \
  {                                                                           \
    _Pragma("unroll")                                                         \
    for (int _j = 0; _j < 4; ++_j) {                                          \
      int _c    = _j * 512 + tid;                                             \
      int _row  = _c >> 3;                                                    \
      int _colb = ((_c & 7) * 16) ^ ((_row & 7) << 4);                        \
      async_copy16((char*)lA[buf] + _j * 8192 + w * 1024,                     \
                   (const char*)(Ab + (size_t)_row * 768 + (k0)) + _colb);    \
      async_copy16((char*)lB[buf] + _j * 8192 + w * 1024,                     \
                   (const char*)(Bb + (size_t)_row * 768 + (k0)) + _colb);    \
    }                                                                         \
  }

#define LOAD_FRAGS(buf, kk)                                                   \
  {                                                                           \
    const char* _bA = (const char*)lA[buf];                                   \
    const char* _bB = (const char*)lB[buf];                                   \
    _Pragma("unroll")                                                         \
    for (int _ks = 0; _ks < 2; ++_ks) {                                       \
      const int _kx = ((kk) * 64 + _ks * 32 + khb) ^ sx;                      \
      _Pragma("unroll")                                                       \
      for (int _mt = 0; _mt < 4; ++_mt)                                       \
        af[_mt][_ks] = *(const bf16x8v*)(_bA + (arow + _mt * 32) * 128 + _kx);\
      _Pragma("unroll")                                                       \
      for (int _nt = 0; _nt < 2; ++_nt)                                       \
        bg[_nt][_ks] = *(const bf16x8v*)(_bB + (brow + _nt * 32) * 128 + _kx);\
    }                                                                         \
  }

#define MFMA_PHASE()                                                          \
  {                                                                           \
    __builtin_amdgcn_s_setprio(1);                                            \
    _Pragma("unroll")                                                         \
    for (int _ks = 0; _ks < 2; ++_ks)                                         \
      _Pragma("unroll")                                                       \
      for (int _mt = 0; _mt < 4; ++_mt)                                       \
        _Pragma("unroll")                                                     \
        for (int _nt = 0; _nt < 2; ++_nt)                                     \
          acc[_mt][_nt] = __builtin_amdgcn_mfma_f32_32x32x16_bf16(            \
              af[_mt][_ks], bg[_nt][_ks], acc[_mt][_nt], 0, 0, 0);            \
    __builtin_amdgcn_s_setprio(0);                                            \
  }

  f32x16 acc[4][2] = {};
  bf16x8v af[4][2], bg[2][2];

  STAGE(0, 0);
  STAGE(1, BK);

  int cur = 0;
  for (int kt = 0; kt < KT; ++kt) {
    if (kt < KT - 1) { WAITV8(); } else { WAITV0(); }
    BAR();

    LOAD_FRAGS(cur, 0);
    WAITL();
    MFMA_PHASE();

    LOAD_FRAGS(cur, 1);
    WAITL();
    BAR();
    if (kt < KT - 2) STAGE(cur, (kt + 2) * BK);
    MFMA_PHASE();

    cur ^= 1;
  }

  float* Cb = C + (size_t)bz * LD * LD;
#pragma unroll
  for (int mt = 0; mt < 4; ++mt) {
    int rowb = tm + wr * 128 + mt * 32 + 4 * (lane >> 5);
#pragma unroll
    for (int nt = 0; nt < 2; ++nt) {
      int col = tn + wc * 64 + nt * 32 + l31;
#pragma unroll
      for (int reg = 0; reg < 16; ++reg) {
        int row = rowb + (reg & 3) + 8 * (reg >> 2);
        Cb[(size_t)row * LD + col] = acc[mt][nt][reg];
      }
    }
  }
#undef STAGE
#undef LOAD_FRAGS
#undef MFMA_PHASE
}

extern "C" void kernel_launch(void* const* d_in, const int* in_sizes, int n_in,
                              void* d_out, int out_size, void* d_ws, size_t ws_size,
                              hipStream_t stream) {
  const float* seq_prev  = (const float*)d_in[0];  // [16][2048][768]
  const float* seq_after = (const float*)d_in[1];  // [16][2048][768]
  const float* W         = (const float*)d_in[2];  // [768][768] (in,out)
  const float* bias      = (const float*)d_in[3];  // [768]
  float* out             = (float*)d_out;          // [16][2048][2048] fp32

  char* ws   = (char*)d_ws;
  short* Wt  = (short*)ws;                         // 768*768*2   = 1179648 B
  short* Pb  = (short*)(ws + 1179648);             // 65536*768*2 = 100663296 B

  constexpr int NSEQ = 16 * 2048 * 768;

  // 1. W transpose + convert
  wt_kernel<<<768 * 768 / 256, 256, 0, stream>>>(W, Wt);

  // 2. feed-forward + relu, conversion fused (768 blocks, XCD-swizzled)
  gemm_ff<<<768, 512, 0, stream>>>(seq_prev, seq_after, Wt, bias, Pb);

  // 3. batched similarity (1024 blocks, XCD-swizzled)
  gemm_sim<<<1024, 512, 0, stream>>>(Pb, Pb + NSEQ, out);
}

// Round 11
// 269.569 us; speedup vs baseline: 1.2074x; 1.0059x over previous
//
#include <hip/hip_runtime.h>
#include <hip/hip_bf16.h>

// sim[b,l,m] = sum_d relu(prev@W+b)[b,l,d] * relu(after@W+b)[b,m,d]
// bz=16, L=2048, d=768.
//
// Pipeline:
//   1. wt_kernel : Wt[n][k] = bf16(W[k][n])                   (ws, 1.2 MB)
//   2. gemm_ff   : Pb = relu(bf16(seq) @ Wt^T + bias) -> bf16 (ws, 96 MB)
//   3. gemm_sim  : sim[b] = Pp[b] @ Pa[b]^T -> fp32 d_out
//
// ROUND 9 KERNEL (proven 271us) with ONE change: LDS XOR swizzle uses
// ((row>>2)&7) instead of (row&7). Old swizzle left rows 0,8,16,24 on the
// same bank slot -> inherent 4-way conflict for 32-row fragment reads
// (SQ_LDS_BANK_CONFLICT 9.4e6). New: slot = 8*(row&3) + (x ^ ((row>>2)&7))
// is bijective over 32 consecutive rows -> conflict-free frag reads.
// Same involution on stage-source, cvt-write, and read (both-sides rule).

typedef __attribute__((ext_vector_type(8)))  short bf16x8v;
typedef __attribute__((ext_vector_type(8)))  short s16x8;
typedef __attribute__((ext_vector_type(16))) float f32x16;
typedef __attribute__((ext_vector_type(4)))  float float4v;

__device__ __forceinline__ unsigned short f2bf(float f) {
  unsigned int u = __float_as_uint(f);
  u += 0x7fffu + ((u >> 16) & 1u);
  return (unsigned short)(u >> 16);
}

__device__ __forceinline__ void async_copy16(void* lds, const void* g) {
  __builtin_amdgcn_global_load_lds(
      (const __attribute__((address_space(1))) void*)g,
      (__attribute__((address_space(3))) void*)lds, 16, 0, 0);
}

// proven macro set (round-5 skeleton)
#define BAR()    asm volatile("s_barrier" ::: "memory")
#define WAITV8() asm volatile("s_waitcnt vmcnt(8)" ::: "memory")
#define WAITV0() asm volatile("s_waitcnt vmcnt(0)" ::: "memory")
#define WAITL()  do { asm volatile("s_waitcnt lgkmcnt(0)" ::: "memory"); \
                      __builtin_amdgcn_sched_barrier(0); } while (0)
// pinned variants (gemm_ff)
#define FBARF()   do { __builtin_amdgcn_sched_barrier(0);                 \
                       __builtin_amdgcn_s_barrier();                      \
                       __builtin_amdgcn_sched_barrier(0); } while (0)
#define FWAITV(n) do { asm volatile("s_waitcnt vmcnt(" #n ")" ::: "memory"); \
                       __builtin_amdgcn_sched_barrier(0); } while (0)
#define FLGKM0()  do { asm volatile("s_waitcnt lgkmcnt(0)" ::: "memory");  \
                       __builtin_amdgcn_sched_barrier(0); } while (0)

// ---------------- W transpose + convert: Wt[n][k] = bf16(W[k][n]) ------------
__global__ void wt_kernel(const float* __restrict__ W, short* __restrict__ Wt) {
  int idx = blockIdx.x * 256 + threadIdx.x;   // n*768 + k
  int n = idx / 768;
  int k = idx - n * 768;
  Wt[idx] = (short)f2bf(W[k * 768 + n]);
}

// ======== gemm_ff: Pb = relu(bf16(seq) @ Wt^T + bias), conversion fused ======
__global__ __launch_bounds__(512, 2)
void gemm_ff(const float* __restrict__ Sprev, const float* __restrict__ Safter,
             const short* __restrict__ Wt, const float* __restrict__ bias,
             short* __restrict__ Out) {
  constexpr int BK = 64, KT = 12;             // K = 768
  __shared__ __align__(16) short lA[2][256 * BK];
  __shared__ __align__(16) short lB[2][256 * BK];

  // T1: XCD-chunked swizzle (768 = 8 * 96, bijective).
  const int bid  = blockIdx.x;                // 0..767
  const int virt = (bid & 7) * 96 + (bid >> 3);
  const int by   = virt / 3;                  // 0..255 (M-tile)
  const int bx   = virt - by * 3;             // 0..2   (N-tile)

  const int tid  = threadIdx.x;
  const int lane = tid & 63;
  const int w    = tid >> 6;
  const int wr   = w >> 2;                    // 0..1 (M half)
  const int wc   = w & 3;                     // 0..3 (N quarter)
  const int tn   = bx * 256;                  // 0,256,512

  const float* Af = (by < 128 ? Sprev : Safter) + (size_t)((by & 127) * 256) * 768;
  const int    tm = by * 256;                 // global output row base

  const int l31  = lane & 31;
  const int khb  = (lane >> 5) * 16;
  const int sx   = ((lane >> 2) & 7) << 4;    // NEW: q = (row>>2)&7 = (lane>>2)&7
  const int arow = wr * 128 + l31;
  const int brow = wc * 64 + l31;

#define FF_LOAD_A(k0)                                                         \
  {                                                                           \
    _Pragma("unroll")                                                         \
    for (int _q = 0; _q < 4; ++_q) {                                          \
      int _seg = _q * 512 + tid;                                              \
      int _row = _seg >> 3;                                                   \
      const float* _g = Af + (size_t)_row * 768 + (k0) + (_seg & 7) * 8;      \
      ar[2 * _q]     = *(const float4v*)_g;                                   \
      ar[2 * _q + 1] = *(const float4v*)(_g + 4);                             \
    }                                                                         \
  }

#define FF_CVT_WRITE(buf)                                                     \
  {                                                                           \
    _Pragma("unroll")                                                         \
    for (int _q = 0; _q < 4; ++_q) {                                          \
      int _seg = _q * 512 + tid;                                              \
      int _row = _seg >> 3;                                                   \
      int _cb  = ((_seg & 7) * 16) ^ (((_row >> 2) & 7) << 4);                \
      s16x8 _o;                                                               \
      _o[0] = (short)f2bf(ar[2 * _q][0]);     _o[1] = (short)f2bf(ar[2 * _q][1]); \
      _o[2] = (short)f2bf(ar[2 * _q][2]);     _o[3] = (short)f2bf(ar[2 * _q][3]); \
      _o[4] = (short)f2bf(ar[2 * _q + 1][0]); _o[5] = (short)f2bf(ar[2 * _q + 1][1]); \
      _o[6] = (short)f2bf(ar[2 * _q + 1][2]); _o[7] = (short)f2bf(ar[2 * _q + 1][3]); \
      *(s16x8*)((char*)lA[buf] + _row * 128 + _cb) = _o;                      \
    }                                                                         \
  }

#define FF_STAGE_B(buf, k0)                                                   \
  {                                                                           \
    _Pragma("unroll")                                                         \
    for (int _j = 0; _j < 4; ++_j) {                                          \
      int _c   = _j * 512 + tid;                                              \
      int _row = _c >> 3;                                                     \
      int _cb  = ((_c & 7) * 16) ^ (((_row >> 2) & 7) << 4);                  \
      async_copy16((char*)lB[buf] + _j * 8192 + w * 1024,                     \
                   (const char*)(Wt + (size_t)(tn + _row) * 768 + (k0)) + _cb); \
    }                                                                         \
  }

#define FF_FRAGS(buf, kk)                                                     \
  {                                                                           \
    const char* _bA = (const char*)lA[buf];                                   \
    const char* _bB = (const char*)lB[buf];                                   \
    _Pragma("unroll")                                                         \
    for (int _ks = 0; _ks < 2; ++_ks) {                                       \
      const int _kx = ((kk) * 64 + _ks * 32 + khb) ^ sx;                      \
      _Pragma("unroll")                                                       \
      for (int _mt = 0; _mt < 4; ++_mt)                                       \
        af[_mt][_ks] = *(const bf16x8v*)(_bA + (arow + _mt * 32) * 128 + _kx);\
      _Pragma("unroll")                                                       \
      for (int _nt = 0; _nt < 2; ++_nt)                                       \
        bg[_nt][_ks] = *(const bf16x8v*)(_bB + (brow + _nt * 32) * 128 + _kx);\
    }                                                                         \
  }

#define FF_MFMA()                                                             \
  {                                                                           \
    __builtin_amdgcn_s_setprio(1);                                            \
    _Pragma("unroll")                                                         \
    for (int _ks = 0; _ks < 2; ++_ks)                                         \
      _Pragma("unroll")                                                       \
      for (int _mt = 0; _mt < 4; ++_mt)                                       \
        _Pragma("unroll")                                                     \
        for (int _nt = 0; _nt < 2; ++_nt)                                     \
          acc[_mt][_nt] = __builtin_amdgcn_mfma_f32_32x32x16_bf16(            \
              af[_mt][_ks], bg[_nt][_ks], acc[_mt][_nt], 0, 0, 0);            \
    __builtin_amdgcn_s_setprio(0);                                            \
  }

  f32x16 acc[4][2] = {};
  bf16x8v af[4][2], bg[2][2];
  float4v ar[8];

  // prologue: A(0) -> regs -> lA[0]; A(1) -> regs; B(0),B(1) staged.
  FF_LOAD_A(0);                               // vm: A0=8
  FWAITV(0);
  FF_CVT_WRITE(0);
  FF_LOAD_A(BK);                              // vm: A1=8
  FF_STAGE_B(0, 0);                           // vm: +B0=4
  FF_STAGE_B(1, BK);                          // vm: +B1=4  (out: 16)
  FLGKM0();                                   // own lA[0] writes done
  FWAITV(4);                                  // retires A1+B0: B0 landed
  FBARF();                                    // tile0 ready for everyone

  for (int kt = 0; kt < KT; ++kt) {
    const int cur = kt & 1, nxt = cur ^ 1;
    FF_FRAGS(cur, 0);                         // 12 ds_read
    if (kt + 1 < KT) {
      FWAITV(4);                              // A(kt+1) landed
      FF_CVT_WRITE(nxt);                      // 4 ds_write -> lA[nxt]
    }
    FLGKM0();                                 // frags + writes done
    FF_MFMA();                                // kk0
    if (kt + 2 < KT) FF_LOAD_A((kt + 2) * BK);  // 8 vm
    FF_FRAGS(cur, 1);                         // 12 ds_read
    FLGKM0();                                 // all reads of buf[cur] done
    if (kt + 1 < KT) {
      if (kt + 2 < KT) { FWAITV(8); }         // B(kt+1) landed
      else             { FWAITV(0); }         // tail drain
      FBARF();                                // tile kt+1 ready; buf[cur] free
      if (kt + 2 < KT) FF_STAGE_B(cur, (kt + 2) * BK);
    }
    FF_MFMA();                                // kk1
  }

  // epilogue: bias+relu -> bf16
#pragma unroll
  for (int mt = 0; mt < 4; ++mt) {
    int rowb = tm + wr * 128 + mt * 32 + 4 * (lane >> 5);
#pragma unroll
    for (int nt = 0; nt < 2; ++nt) {
      int col = tn + wc * 64 + nt * 32 + l31;
      float bv = bias[col];
#pragma unroll
      for (int reg = 0; reg < 16; ++reg) {
        int row = rowb + (reg & 3) + 8 * (reg >> 2);
        float v = fmaxf(acc[mt][nt][reg] + bv, 0.0f);
        Out[(size_t)row * 768 + col] = (short)f2bf(v);
      }
    }
  }
#undef FF_LOAD_A
#undef FF_CVT_WRITE
#undef FF_STAGE_B
#undef FF_FRAGS
#undef FF_MFMA
}

// ======== gemm_sim: sim[b] = Pp[b] @ Pa[b]^T (round-5 kernel + T1) ==========
__global__ __launch_bounds__(512, 2)
void gemm_sim(const short* __restrict__ A, const short* __restrict__ B,
              float* __restrict__ C) {
  constexpr int BK = 64, KT = 12, LD = 2048;  // K = 768
  __shared__ __align__(16) short lA[2][256 * BK];
  __shared__ __align__(16) short lB[2][256 * BK];

  // T1: XCD-chunked swizzle (1024 = 8 * 128, bijective).
  const int bid  = blockIdx.x;                // 0..1023
  const int virt = (bid & 7) * 128 + (bid >> 3);
  const int bz   = virt >> 6;                 // 0..15 batch
  const int by   = (virt >> 3) & 7;           // M-tile
  const int bx   = virt & 7;                  // N-tile

  const int tid  = threadIdx.x;
  const int lane = tid & 63;
  const int w    = tid >> 6;
  const int wr   = w >> 2;
  const int wc   = w & 3;
  const int tm   = by * 256;
  const int tn   = bx * 256;

  const short* Ab = A + (size_t)bz * LD * 768 + (size_t)tm * 768;
  const short* Bb = B + (size_t)bz * LD * 768 + (size_t)tn * 768;

  const int l31  = lane & 31;
  const int khb  = (lane >> 5) * 16;
  const int sx   = ((lane >> 2) & 7) << 4;    // NEW swizzle bits
  const int arow = wr * 128 + l31;
  const int brow = wc * 64 + l31;

#define STAGE(buf, k0)                                                        \
  {                                                                           \
    _Pragma("unroll")                                                         \
    for (int _j = 0; _j < 4; ++_j) {                                          \
      int _c    = _j * 512 + tid;                                             \
      int _row  = _c >> 3;                                                    \
      int _colb = ((_c & 7) * 16) ^ (((_row >> 2) & 7) << 4);                 \
      async_copy16((char*)lA[buf] + _j * 8192 + w * 1024,                     \
                   (const char*)(Ab + (size_t)_row * 768 + (k0)) + _colb);    \
      async_copy16((char*)lB[buf] + _j * 8192 + w * 1024,                     \
                   (const char*)(Bb + (size_t)_row * 768 + (k0)) + _colb);    \
    }                                                                         \
  }

#define LOAD_FRAGS(buf, kk)                                                   \
  {                                                                           \
    const char* _bA = (const char*)lA[buf];                                   \
    const char* _bB = (const char*)lB[buf];                                   \
    _Pragma("unroll")                                                         \
    for (int _ks = 0; _ks < 2; ++_ks) {                                       \
      const int _kx = ((kk) * 64 + _ks * 32 + khb) ^ sx;                      \
      _Pragma("unroll")                                                       \
      for (int _mt = 0; _mt < 4; ++_mt)                                       \
        af[_mt][_ks] = *(const bf16x8v*)(_bA + (arow + _mt * 32) * 128 + _kx);\
      _Pragma("unroll")                                                       \
      for (int _nt = 0; _nt < 2; ++_nt)                                       \
        bg[_nt][_ks] = *(const bf16x8v*)(_bB + (brow + _nt * 32) * 128 + _kx);\
    }                                                                         \
  }

#define MFMA_PHASE()                                                          \
  {                                                                           \
    __builtin_amdgcn_s_setprio(1);                                            \
    _Pragma("unroll")                                                         \
    for (int _ks = 0; _ks < 2; ++_ks)                                         \
      _Pragma("unroll")                                                       \
      for (int _mt = 0; _mt < 4; ++_mt)                                       \
        _Pragma("unroll")                                                     \
        for (int _nt = 0; _nt < 2; ++_nt)                                     \
          acc[_mt][_nt] = __builtin_amdgcn_mfma_f32_32x32x16_bf16(            \
              af[_mt][_ks], bg[_nt][_ks], acc[_mt][_nt], 0, 0, 0);            \
    __builtin_amdgcn_s_setprio(0);                                            \
  }

  f32x16 acc[4][2] = {};
  bf16x8v af[4][2], bg[2][2];

  STAGE(0, 0);
  STAGE(1, BK);

  int cur = 0;
  for (int kt = 0; kt < KT; ++kt) {
    if (kt < KT - 1) { WAITV8(); } else { WAITV0(); }
    BAR();

    LOAD_FRAGS(cur, 0);
    WAITL();
    MFMA_PHASE();

    LOAD_FRAGS(cur, 1);
    WAITL();
    BAR();
    if (kt < KT - 2) STAGE(cur, (kt + 2) * BK);
    MFMA_PHASE();

    cur ^= 1;
  }

  float* Cb = C + (size_t)bz * LD * LD;
#pragma unroll
  for (int mt = 0; mt < 4; ++mt) {
    int rowb = tm + wr * 128 + mt * 32 + 4 * (lane >> 5);
#pragma unroll
    for (int nt = 0; nt < 2; ++nt) {
      int col = tn + wc * 64 + nt * 32 + l31;
#pragma unroll
      for (int reg = 0; reg < 16; ++reg) {
        int row = rowb + (reg & 3) + 8 * (reg >> 2);
        Cb[(size_t)row * LD + col] = acc[mt][nt][reg];
      }
    }
  }
#undef STAGE
#undef LOAD_FRAGS
#undef MFMA_PHASE
}

extern "C" void kernel_launch(void* const* d_in, const int* in_sizes, int n_in,
                              void* d_out, int out_size, void* d_ws, size_t ws_size,
                              hipStream_t stream) {
  const float* seq_prev  = (const float*)d_in[0];  // [16][2048][768]
  const float* seq_after = (const float*)d_in[1];  // [16][2048][768]
  const float* W         = (const float*)d_in[2];  // [768][768] (in,out)
  const float* bias      = (const float*)d_in[3];  // [768]
  float* out             = (float*)d_out;          // [16][2048][2048] fp32

  char* ws   = (char*)d_ws;
  short* Wt  = (short*)ws;                         // 768*768*2   = 1179648 B
  short* Pb  = (short*)(ws + 1179648);             // 65536*768*2 = 100663296 B

  constexpr int NSEQ = 16 * 2048 * 768;

  // 1. W transpose + convert
  wt_kernel<<<768 * 768 / 256, 256, 0, stream>>>(W, Wt);

  // 2. feed-forward + relu, conversion fused (768 blocks, XCD-swizzled)
  gemm_ff<<<768, 512, 0, stream>>>(seq_prev, seq_after, Wt, bias, Pb);

  // 3. batched similarity (1024 blocks, XCD-swizzled)
  gemm_sim<<<1024, 512, 0, stream>>>(Pb, Pb + NSEQ, out);
}